// Round 2
// baseline (448.029 us; speedup 1.0000x reference)
//
#include <hip/hip_runtime.h>
#include <hip/hip_bf16.h>

typedef unsigned short u16;
typedef unsigned int   u32;
typedef __attribute__((ext_vector_type(8))) short bf16x8;
typedef __attribute__((ext_vector_type(4))) float f32x4;

__device__ __forceinline__ u32 pack2bf(float a, float b) {
    __hip_bfloat162 h = __float22bfloat162_rn(make_float2(a, b));  // -> v_cvt_pk_bf16_f32
    return *reinterpret_cast<u32*>(&h);
}

__device__ __forceinline__ u16 f2bf(float x) {
    u32 u = __float_as_uint(x);
    u32 r = u + 0x7FFFu + ((u >> 16) & 1u);
    return (u16)(r >> 16);
}

// d_ws layout: w1t = bf16 W1^T [c=256][d=128] (d contiguous), then w2t = bf16 W2^T [e=256][c=256] (c contiguous)
__global__ __launch_bounds__(256) void prep_weights(
    const float* __restrict__ W1, const float* __restrict__ W2,
    u16* __restrict__ w1t, u16* __restrict__ w2t)
{
    int tid = blockIdx.x * 256 + threadIdx.x;
    if (tid < 128 * 256) {
        int c = tid >> 7, d = tid & 127;
        w1t[tid] = f2bf(W1[d * 256 + c]);
    } else {
        int t2 = tid - 128 * 256;
        if (t2 < 256 * 256) {
            int e = t2 >> 8, c = t2 & 255;
            w2t[t2] = f2bf(W2[c * 256 + e]);
        }
    }
}

// One block = one batch b: 64 nodes, 4 waves. LDS is a single 32KB arena with
// three disjoint-lifetime tenants: xt (16KB) -> h1s (32KB) -> partl (1KB).
// 32768B/block => 5 blocks/CU (20 waves/CU).
__global__ __launch_bounds__(256, 5) void fused_mlp(
    const float* __restrict__ X,
    const float* __restrict__ b1, const float* __restrict__ b2,
    const float* __restrict__ W3, const float* __restrict__ b3,
    const u16* __restrict__ w1t, const u16* __restrict__ w2t,
    float* __restrict__ out)
{
    __shared__ u16 smem[64 * 256];    // 32 KB arena
    u16* xt   = smem;                 // bf16 XT[n][d], 16B-chunk XOR-swizzled by (n&15); dies after L1 MFMAs
    u16* h1s  = smem;                 // bf16 h1[n][c], same swizzle; dies after L2 MFMAs
    float* partl = (float*)smem;      // [4][64] per-wave logit partials

    const int tid = threadIdx.x;
    const int w   = tid >> 6;         // wave 0..3
    const int l   = tid & 63;         // lane
    const int lc  = l & 15;           // MFMA col / row-low lane field
    const int lk  = l >> 4;           // MFMA k-group
    const int b   = blockIdx.x;
    const float* Xb = X + (size_t)b * 8192;

    // ---------- phase 0: X[b] (d-major, n contiguous) -> LDS XT[n][d] bf16 ----------
    #pragma unroll
    for (int it = 0; it < 4; ++it) {
        const int dc = w + 4 * it;        // d-chunk 0..15
        const int d0 = dc << 3;
        float v[8];
        #pragma unroll
        for (int j = 0; j < 8; ++j) v[j] = Xb[(d0 + j) * 64 + l];   // coalesced per j across lanes
        u32 pk[4];
        #pragma unroll
        for (int j = 0; j < 4; ++j) pk[j] = pack2bf(v[2 * j], v[2 * j + 1]);
        *(uint4*)(xt + l * 128 + ((dc ^ lc) << 3)) = make_uint4(pk[0], pk[1], pk[2], pk[3]);
    }
    __syncthreads();

    // ---------- layer 1:  D1[c][n] = sum_d W1T[c][d] * XT[n][d] ----------
    f32x4 acc[4][4];
    #pragma unroll
    for (int mt = 0; mt < 4; ++mt)
        #pragma unroll
        for (int nt = 0; nt < 4; ++nt) acc[mt][nt] = (f32x4){0.f, 0.f, 0.f, 0.f};

    #pragma unroll
    for (int ks = 0; ks < 4; ++ks) {                 // K = 128 in 4 steps of 32
        bf16x8 afr[4], bfr[4];
        #pragma unroll
        for (int mt = 0; mt < 4; ++mt)               // A: W1T row c = 64w+16mt+lc, k-contig
            afr[mt] = *(const bf16x8*)(w1t + (64 * w + 16 * mt + lc) * 128 + 32 * ks + 8 * lk);
        #pragma unroll
        for (int nt = 0; nt < 4; ++nt) {             // B: XT[n][d], col n = 16nt+lc
            const int n = 16 * nt + lc;
            bfr[nt] = *(const bf16x8*)(xt + n * 128 + (((4 * ks + lk) ^ lc) << 3));
        }
        #pragma unroll
        for (int mt = 0; mt < 4; ++mt)
            #pragma unroll
            for (int nt = 0; nt < 4; ++nt)
                acc[mt][nt] = __builtin_amdgcn_mfma_f32_16x16x32_bf16(afr[mt], bfr[nt], acc[mt][nt], 0, 0, 0);
    }
    __syncthreads();   // all waves done READING xt before we overwrite it with h1

    // epilogue 1: +b1, relu, bf16, packed 8B store to h1[n][c] (4 consecutive c per lane)
    #pragma unroll
    for (int mt = 0; mt < 4; ++mt) {
        const int c0 = 64 * w + 16 * mt + 4 * lk;    // D-row base: c = c0 + reg
        const float4 bv = *(const float4*)(b1 + c0);
        #pragma unroll
        for (int nt = 0; nt < 4; ++nt) {
            const int n = 16 * nt + lc;              // D-col: n
            float x0 = fmaxf(acc[mt][nt][0] + bv.x, 0.f);
            float x1 = fmaxf(acc[mt][nt][1] + bv.y, 0.f);
            float x2 = fmaxf(acc[mt][nt][2] + bv.z, 0.f);
            float x3 = fmaxf(acc[mt][nt][3] + bv.w, 0.f);
            u32 lo = pack2bf(x0, x1);
            u32 hi = pack2bf(x2, x3);
            const int chunk = (c0 >> 3) ^ lc;        // 5-bit chunk, XOR low 4 bits
            *(uint2*)(h1s + n * 256 + (chunk << 3) + (c0 & 7)) = make_uint2(lo, hi);
        }
    }
    __syncthreads();

    // ---------- layer 2:  D2[n][e] = sum_c h1[n][c] * W2T[e][c] ----------
    f32x4 acc2[4][4];
    #pragma unroll
    for (int mt = 0; mt < 4; ++mt)
        #pragma unroll
        for (int nt = 0; nt < 4; ++nt) acc2[mt][nt] = (f32x4){0.f, 0.f, 0.f, 0.f};

    #pragma unroll
    for (int ks = 0; ks < 8; ++ks) {                 // K = 256 in 8 steps of 32
        bf16x8 afr[4], bfr[4];
        #pragma unroll
        for (int mt = 0; mt < 4; ++mt) {             // A: h1[n][c], row n = 16mt+lc, k-contig c
            const int n = 16 * mt + lc;
            afr[mt] = *(const bf16x8*)(h1s + n * 256 + (((4 * ks + lk) ^ lc) << 3));
        }
        #pragma unroll
        for (int nt = 0; nt < 4; ++nt)               // B: W2T row e = 64w+16nt+lc, k-contig c
            bfr[nt] = *(const bf16x8*)(w2t + (64 * w + 16 * nt + lc) * 256 + 32 * ks + 8 * lk);
        #pragma unroll
        for (int mt = 0; mt < 4; ++mt)
            #pragma unroll
            for (int nt = 0; nt < 4; ++nt)
                acc2[mt][nt] = __builtin_amdgcn_mfma_f32_16x16x32_bf16(afr[mt], bfr[nt], acc2[mt][nt], 0, 0, 0);
    }
    __syncthreads();   // all waves done READING h1s before partl overwrites the arena

    // ---------- layer 3: +b2, relu, dot with W3, reduce over e ----------
    float b2v[4], w3v[4];
    #pragma unroll
    for (int nt = 0; nt < 4; ++nt) {
        const int e = 64 * w + 16 * nt + lc;
        b2v[nt] = b2[e];
        w3v[nt] = W3[e];
    }
    #pragma unroll
    for (int mt = 0; mt < 4; ++mt) {
        #pragma unroll
        for (int j = 0; j < 4; ++j) {                // D2 row n = 16mt + 4lk + j
            float s = 0.f;
            #pragma unroll
            for (int nt = 0; nt < 4; ++nt)
                s += fmaxf(acc2[mt][nt][j] + b2v[nt], 0.f) * w3v[nt];
            s += __shfl_xor(s, 1);
            s += __shfl_xor(s, 2);
            s += __shfl_xor(s, 4);
            s += __shfl_xor(s, 8);                   // sum over the 16 e-lanes
            if (lc == 0) partl[w * 64 + 16 * mt + 4 * lk + j] = s;
        }
    }
    __syncthreads();

    if (tid < 64) {
        float s = partl[0 * 64 + tid] + partl[1 * 64 + tid] + partl[2 * 64 + tid] + partl[3 * 64 + tid] + b3[0];
        out[(size_t)b * 65 + 1 + tid] = s;
    } else if (tid == 64) {
        out[(size_t)b * 65] = 0.f;                   // add_zero column
    }
}

extern "C" void kernel_launch(void* const* d_in, const int* in_sizes, int n_in,
                              void* d_out, int out_size, void* d_ws, size_t ws_size,
                              hipStream_t stream) {
    const float* X  = (const float*)d_in[0];
    const float* W1 = (const float*)d_in[1];
    const float* b1 = (const float*)d_in[2];
    const float* W2 = (const float*)d_in[3];
    const float* b2 = (const float*)d_in[4];
    const float* W3 = (const float*)d_in[5];
    const float* b3 = (const float*)d_in[6];
    float* out = (float*)d_out;

    u16* w1t = (u16*)d_ws;            // 256*128 bf16 = 64 KB
    u16* w2t = w1t + 256 * 128;       // 256*256 bf16 = 128 KB

    const int B = in_sizes[0] / (128 * 64);   // 8192

    prep_weights<<<384, 256, 0, stream>>>(W1, W2, w1t, w2t);
    fused_mlp<<<B, 256, 0, stream>>>(X, b1, b2, W3, b3, w1t, w2t, out);
}

// Round 3
// 201.690 us; speedup vs baseline: 2.2214x; 2.2214x over previous
//
#include <hip/hip_runtime.h>
#include <hip/hip_bf16.h>

typedef unsigned short u16;
typedef unsigned int   u32;
typedef __attribute__((ext_vector_type(8))) short bf16x8;
typedef __attribute__((ext_vector_type(4))) float f32x4;

__device__ __forceinline__ u32 pack2bf(float a, float b) {
    __hip_bfloat162 h = __float22bfloat162_rn(make_float2(a, b));  // -> v_cvt_pk_bf16_f32
    return *reinterpret_cast<u32*>(&h);
}

__device__ __forceinline__ u16 f2bf(float x) {
    u32 u = __float_as_uint(x);
    u32 r = u + 0x7FFFu + ((u >> 16) & 1u);
    return (u16)(r >> 16);
}

// d_ws layout: w1t = bf16 W1^T [c=256][d=128] (d contiguous), then w2t = bf16 W2^T [e=256][c=256] (c contiguous)
__global__ __launch_bounds__(256) void prep_weights(
    const float* __restrict__ W1, const float* __restrict__ W2,
    u16* __restrict__ w1t, u16* __restrict__ w2t)
{
    int tid = blockIdx.x * 256 + threadIdx.x;
    if (tid < 128 * 256) {
        int c = tid >> 7, d = tid & 127;
        w1t[tid] = f2bf(W1[d * 256 + c]);
    } else {
        int t2 = tid - 128 * 256;
        if (t2 < 256 * 256) {
            int e = t2 >> 8, c = t2 & 255;
            w2t[t2] = f2bf(W2[c * 256 + e]);
        }
    }
}

// One block = one batch b: 64 nodes, 4 waves. 32KB LDS arena, disjoint-lifetime
// tenants: xt (16KB) -> h1s (32KB) -> partl (1KB).
// __launch_bounds__(256,4): cap ~128 regs/wave -> 4 waves/SIMD (4 blocks/CU).
// (256,5) spilled ~1GB to scratch in R2 — acc live-set (~130) can't fit 102.
__global__ __launch_bounds__(256, 4) void fused_mlp(
    const float* __restrict__ X,
    const float* __restrict__ b1, const float* __restrict__ b2,
    const float* __restrict__ W3, const float* __restrict__ b3,
    const u16* __restrict__ w1t, const u16* __restrict__ w2t,
    float* __restrict__ out)
{
    __shared__ u16 smem[64 * 256];    // 32 KB arena
    u16* xt   = smem;                 // bf16 XT[n][d], 16B-chunk XOR-swizzled by (n&15); dies after L1 MFMAs
    u16* h1s  = smem;                 // bf16 h1[n][c], same swizzle; dies after L2 MFMAs
    float* partl = (float*)smem;      // [4][64] per-wave logit partials

    const int tid = threadIdx.x;
    const int w   = tid >> 6;         // wave 0..3
    const int l   = tid & 63;         // lane
    const int lc  = l & 15;           // MFMA col / row-low lane field
    const int lk  = l >> 4;           // MFMA k-group
    const int b   = blockIdx.x;
    const float* Xb = X + (size_t)b * 8192;

    // ---------- phase 0: X[b] (d-major, n contiguous) -> LDS XT[n][d] bf16 ----------
    #pragma unroll
    for (int it = 0; it < 4; ++it) {
        const int dc = w + 4 * it;        // d-chunk 0..15
        const int d0 = dc << 3;
        float v[8];
        #pragma unroll
        for (int j = 0; j < 8; ++j) v[j] = Xb[(d0 + j) * 64 + l];   // coalesced per j across lanes
        u32 pk[4];
        #pragma unroll
        for (int j = 0; j < 4; ++j) pk[j] = pack2bf(v[2 * j], v[2 * j + 1]);
        *(uint4*)(xt + l * 128 + ((dc ^ lc) << 3)) = make_uint4(pk[0], pk[1], pk[2], pk[3]);
    }

    // hoist ks=0 A-frag loads (global/L2) above the barrier: latency overlaps barrier wait
    bf16x8 afrN[4];
    #pragma unroll
    for (int mt = 0; mt < 4; ++mt)
        afrN[mt] = *(const bf16x8*)(w1t + (64 * w + 16 * mt + lc) * 128 + 8 * lk);
    __syncthreads();

    // ---------- layer 1:  D1[c][n] = sum_d W1T[c][d] * XT[n][d] ----------
    f32x4 acc[4][4];
    #pragma unroll
    for (int mt = 0; mt < 4; ++mt)
        #pragma unroll
        for (int nt = 0; nt < 4; ++nt) acc[mt][nt] = (f32x4){0.f, 0.f, 0.f, 0.f};

    #pragma unroll
    for (int ks = 0; ks < 4; ++ks) {                 // K = 128 in 4 steps of 32
        bf16x8 afr[4], bfr[4];
        #pragma unroll
        for (int mt = 0; mt < 4; ++mt) afr[mt] = afrN[mt];
        if (ks < 3) {                                // prefetch next-ks A-frags (L2 latency hidden under MFMAs)
            #pragma unroll
            for (int mt = 0; mt < 4; ++mt)
                afrN[mt] = *(const bf16x8*)(w1t + (64 * w + 16 * mt + lc) * 128 + 32 * (ks + 1) + 8 * lk);
        }
        #pragma unroll
        for (int nt = 0; nt < 4; ++nt) {             // B: XT[n][d], col n = 16nt+lc
            const int n = 16 * nt + lc;
            bfr[nt] = *(const bf16x8*)(xt + n * 128 + (((4 * ks + lk) ^ lc) << 3));
        }
        #pragma unroll
        for (int mt = 0; mt < 4; ++mt)
            #pragma unroll
            for (int nt = 0; nt < 4; ++nt)
                acc[mt][nt] = __builtin_amdgcn_mfma_f32_16x16x32_bf16(afr[mt], bfr[nt], acc[mt][nt], 0, 0, 0);
    }
    __syncthreads();   // all waves done READING xt before we overwrite it with h1

    // epilogue 1: +b1, relu, bf16, packed 8B store to h1[n][c] (4 consecutive c per lane)
    #pragma unroll
    for (int mt = 0; mt < 4; ++mt) {
        const int c0 = 64 * w + 16 * mt + 4 * lk;    // D-row base: c = c0 + reg
        const float4 bv = *(const float4*)(b1 + c0);
        #pragma unroll
        for (int nt = 0; nt < 4; ++nt) {
            const int n = 16 * nt + lc;              // D-col: n
            float x0 = fmaxf(acc[mt][nt][0] + bv.x, 0.f);
            float x1 = fmaxf(acc[mt][nt][1] + bv.y, 0.f);
            float x2 = fmaxf(acc[mt][nt][2] + bv.z, 0.f);
            float x3 = fmaxf(acc[mt][nt][3] + bv.w, 0.f);
            u32 lo = pack2bf(x0, x1);
            u32 hi = pack2bf(x2, x3);
            const int chunk = (c0 >> 3) ^ lc;        // 5-bit chunk, XOR low 4 bits
            *(uint2*)(h1s + n * 256 + (chunk << 3) + (c0 & 7)) = make_uint2(lo, hi);
        }
    }

    // hoist ks=0 B-frag loads (w2t, global/L2) above the barrier
    bf16x8 bfrN[4];
    #pragma unroll
    for (int nt = 0; nt < 4; ++nt)
        bfrN[nt] = *(const bf16x8*)(w2t + (64 * w + 16 * nt + lc) * 256 + 8 * lk);
    __syncthreads();

    // ---------- layer 2:  D2[n][e] = sum_c h1[n][c] * W2T[e][c] ----------
    f32x4 acc2[4][4];
    #pragma unroll
    for (int mt = 0; mt < 4; ++mt)
        #pragma unroll
        for (int nt = 0; nt < 4; ++nt) acc2[mt][nt] = (f32x4){0.f, 0.f, 0.f, 0.f};

    #pragma unroll
    for (int ks = 0; ks < 8; ++ks) {                 // K = 256 in 8 steps of 32
        bf16x8 afr[4], bfr[4];
        #pragma unroll
        for (int nt = 0; nt < 4; ++nt) bfr[nt] = bfrN[nt];
        if (ks < 7) {                                // prefetch next-ks w2t frags
            #pragma unroll
            for (int nt = 0; nt < 4; ++nt)
                bfrN[nt] = *(const bf16x8*)(w2t + (64 * w + 16 * nt + lc) * 256 + 32 * (ks + 1) + 8 * lk);
        }
        #pragma unroll
        for (int mt = 0; mt < 4; ++mt) {             // A: h1[n][c], row n = 16mt+lc, k-contig c
            const int n = 16 * mt + lc;
            afr[mt] = *(const bf16x8*)(h1s + n * 256 + (((4 * ks + lk) ^ lc) << 3));
        }
        #pragma unroll
        for (int mt = 0; mt < 4; ++mt)
            #pragma unroll
            for (int nt = 0; nt < 4; ++nt)
                acc2[mt][nt] = __builtin_amdgcn_mfma_f32_16x16x32_bf16(afr[mt], bfr[nt], acc2[mt][nt], 0, 0, 0);
    }
    __syncthreads();   // all waves done READING h1s before partl overwrites the arena

    // ---------- layer 3: +b2, relu, dot with W3, reduce over e ----------
    float b2v[4], w3v[4];
    #pragma unroll
    for (int nt = 0; nt < 4; ++nt) {
        const int e = 64 * w + 16 * nt + lc;
        b2v[nt] = b2[e];
        w3v[nt] = W3[e];
    }
    #pragma unroll
    for (int mt = 0; mt < 4; ++mt) {
        #pragma unroll
        for (int j = 0; j < 4; ++j) {                // D2 row n = 16mt + 4lk + j
            float s = 0.f;
            #pragma unroll
            for (int nt = 0; nt < 4; ++nt)
                s += fmaxf(acc2[mt][nt][j] + b2v[nt], 0.f) * w3v[nt];
            s += __shfl_xor(s, 1);
            s += __shfl_xor(s, 2);
            s += __shfl_xor(s, 4);
            s += __shfl_xor(s, 8);                   // sum over the 16 e-lanes
            if (lc == 0) partl[w * 64 + 16 * mt + 4 * lk + j] = s;
        }
    }
    __syncthreads();

    if (tid < 64) {
        float s = partl[0 * 64 + tid] + partl[1 * 64 + tid] + partl[2 * 64 + tid] + partl[3 * 64 + tid] + b3[0];
        out[(size_t)b * 65 + 1 + tid] = s;
    } else if (tid == 64) {
        out[(size_t)b * 65] = 0.f;                   // add_zero column
    }
}

extern "C" void kernel_launch(void* const* d_in, const int* in_sizes, int n_in,
                              void* d_out, int out_size, void* d_ws, size_t ws_size,
                              hipStream_t stream) {
    const float* X  = (const float*)d_in[0];
    const float* W1 = (const float*)d_in[1];
    const float* b1 = (const float*)d_in[2];
    const float* W2 = (const float*)d_in[3];
    const float* b2 = (const float*)d_in[4];
    const float* W3 = (const float*)d_in[5];
    const float* b3 = (const float*)d_in[6];
    float* out = (float*)d_out;

    u16* w1t = (u16*)d_ws;            // 256*128 bf16 = 64 KB
    u16* w2t = w1t + 256 * 128;       // 256*256 bf16 = 128 KB

    const int B = in_sizes[0] / (128 * 64);   // 8192

    prep_weights<<<384, 256, 0, stream>>>(W1, W2, w1t, w2t);
    fused_mlp<<<B, 256, 0, stream>>>(X, b1, b2, W3, b3, w1t, w2t, out);
}